// Round 2
// baseline (5815.778 us; speedup 1.0000x reference)
//
#include <hip/hip_runtime.h>
#include <float.h>

#define N_Q 8192
#define M_PTS 50000
#define DIM 128
#define KNN 10
#define NCLS 10
#define SPLITS 16
#define PTS_PER_SPLIT (M_PTS / SPLITS)  // 3125
#define Q_PER_BLOCK 64                  // 4 waves x 16 queries

// ---------------------------------------------------------------------------
// Phase 0: y2[j] = ||train_pts[j]||^2.  32 lanes per row, fully coalesced.
// ---------------------------------------------------------------------------
__global__ __launch_bounds__(256) void y2_kernel(const float4* __restrict__ y,
                                                 float* __restrict__ y2) {
    int t = blockIdx.x * 256 + threadIdx.x;   // one float4 per thread
    int row = t >> 5;
    int lane32 = t & 31;
    float4 v = y[t];
    float p = v.x * v.x + v.y * v.y + v.z * v.z + v.w * v.w;
    #pragma unroll
    for (int off = 16; off > 0; off >>= 1) p += __shfl_xor(p, off, 64);
    if (lane32 == 0) y2[row] = p;
}

// Stable (ties keep earlier entry) predicated top-K insert; caller checks
// s < ts[KNN-1]. All indices compile-time -> stays in registers.
__device__ __forceinline__ void topk_insert(float (&ts)[KNN], int (&tl)[KNN],
                                            float s, int lab) {
    #pragma unroll
    for (int p = KNN - 1; p >= 1; --p) {
        bool stay = ts[p] <= s;
        bool from_prev = ts[p - 1] > s;
        ts[p] = stay ? ts[p] : (from_prev ? ts[p - 1] : s);
        tl[p] = stay ? tl[p] : (from_prev ? tl[p - 1] : lab);
    }
    if (ts[0] > s) { ts[0] = s; tl[0] = lab; }
}

// ---------------------------------------------------------------------------
// Phase 1: dim-split layout. Each wave handles 16 queries; lane = chunk*16+qh
// where chunk (lane>>4) owns dims [chunk*32, chunk*32+32). Query slice is 8
// float4 = 32 VGPRs (register-resident by construction). Dot finished with
// two shfl_xor; all 4 chunk-copies keep the top-k redundantly (no divergence
// penalty), chunk 0 writes the partial.
// ---------------------------------------------------------------------------
__global__ __launch_bounds__(256, 4) void knn_partial(
    const float* __restrict__ x, const float* __restrict__ y,
    const int* __restrict__ labels, const float* __restrict__ y2,
    float* __restrict__ pscore, int* __restrict__ plabel) {
    const int lane  = threadIdx.x & 63;
    const int wid   = threadIdx.x >> 6;     // wave in block, 0..3
    const int chunk = lane >> 4;            // 0..3: which 32-dim slice
    const int qh    = lane & 15;            // query within wave
    const int q     = blockIdx.x * Q_PER_BLOCK + wid * 16 + qh;
    const int split = blockIdx.y;
    const int j0 = split * PTS_PER_SPLIT;
    const int j1 = j0 + PTS_PER_SPLIT;

    const float4* xrow = (const float4*)(x + (size_t)q * DIM + chunk * 32);
    float4 xq[8];
    #pragma unroll
    for (int i = 0; i < 8; ++i) xq[i] = xrow[i];

    float ts[KNN];
    int   tl[KNN];
    #pragma unroll
    for (int i = 0; i < KNN; ++i) { ts[i] = FLT_MAX; tl[i] = 0; }

    #pragma unroll 2
    for (int j = j0; j < j1; ++j) {
        const float4* yrow = (const float4*)(y + (size_t)j * DIM + chunk * 32);
        float4 v0 = yrow[0];
        float4 v1 = yrow[1];
        float4 v2 = yrow[2];
        float4 v3 = yrow[3];
        float4 v4 = yrow[4];
        float4 v5 = yrow[5];
        float4 v6 = yrow[6];
        float4 v7 = yrow[7];
        float a0 = 0.f, a1 = 0.f, a2 = 0.f, a3 = 0.f;
        a0 = fmaf(xq[0].x, v0.x, a0); a0 = fmaf(xq[0].y, v0.y, a0);
        a0 = fmaf(xq[0].z, v0.z, a0); a0 = fmaf(xq[0].w, v0.w, a0);
        a1 = fmaf(xq[1].x, v1.x, a1); a1 = fmaf(xq[1].y, v1.y, a1);
        a1 = fmaf(xq[1].z, v1.z, a1); a1 = fmaf(xq[1].w, v1.w, a1);
        a2 = fmaf(xq[2].x, v2.x, a2); a2 = fmaf(xq[2].y, v2.y, a2);
        a2 = fmaf(xq[2].z, v2.z, a2); a2 = fmaf(xq[2].w, v2.w, a2);
        a3 = fmaf(xq[3].x, v3.x, a3); a3 = fmaf(xq[3].y, v3.y, a3);
        a3 = fmaf(xq[3].z, v3.z, a3); a3 = fmaf(xq[3].w, v3.w, a3);
        a0 = fmaf(xq[4].x, v4.x, a0); a0 = fmaf(xq[4].y, v4.y, a0);
        a0 = fmaf(xq[4].z, v4.z, a0); a0 = fmaf(xq[4].w, v4.w, a0);
        a1 = fmaf(xq[5].x, v5.x, a1); a1 = fmaf(xq[5].y, v5.y, a1);
        a1 = fmaf(xq[5].z, v5.z, a1); a1 = fmaf(xq[5].w, v5.w, a1);
        a2 = fmaf(xq[6].x, v6.x, a2); a2 = fmaf(xq[6].y, v6.y, a2);
        a2 = fmaf(xq[6].z, v6.z, a2); a2 = fmaf(xq[6].w, v6.w, a2);
        a3 = fmaf(xq[7].x, v7.x, a3); a3 = fmaf(xq[7].y, v7.y, a3);
        a3 = fmaf(xq[7].z, v7.z, a3); a3 = fmaf(xq[7].w, v7.w, a3);
        float p = (a0 + a1) + (a2 + a3);
        p += __shfl_xor(p, 16, 64);
        p += __shfl_xor(p, 32, 64);          // all lanes now hold full dot
        float s = y2[j] - 2.0f * p;          // x^2 const + sqrt dropped (order-preserving)
        if (s < ts[KNN - 1]) {
            topk_insert(ts, tl, s, labels[j]);
        }
    }

    if (chunk == 0) {
        size_t base = ((size_t)q * SPLITS + split) * KNN;
        #pragma unroll
        for (int i = 0; i < KNN; ++i) {
            pscore[base + i] = ts[i];
            plabel[base + i] = tl[i];
        }
    }
}

// ---------------------------------------------------------------------------
// Phase 2: merge SPLITS sorted partial top-10s per query (stable: exact ties
// resolve to lowest original index like jax top_k), then majority vote with
// ties to the LARGEST class (reference reversed-argmax).
// ---------------------------------------------------------------------------
__global__ __launch_bounds__(256) void knn_final(const float* __restrict__ pscore,
                                                 const int* __restrict__ plabel,
                                                 int* __restrict__ out) {
    const int q = blockIdx.x * 256 + threadIdx.x;
    float ts[KNN];
    int   tl[KNN];
    #pragma unroll
    for (int i = 0; i < KNN; ++i) { ts[i] = FLT_MAX; tl[i] = 0; }

    size_t base = (size_t)q * SPLITS * KNN;
    for (int e = 0; e < SPLITS * KNN; ++e) {
        float s = pscore[base + e];
        if (s < ts[KNN - 1]) {
            topk_insert(ts, tl, s, plabel[base + e]);
        }
    }

    int bestc = 0, bestn = -1;
    #pragma unroll
    for (int c = 0; c < NCLS; ++c) {
        int n = 0;
        #pragma unroll
        for (int i = 0; i < KNN; ++i) n += (tl[i] == c) ? 1 : 0;
        if (n >= bestn) { bestn = n; bestc = c; }   // >= : ties -> larger label
    }
    out[q] = bestc;
}

// ---------------------------------------------------------------------------
extern "C" void kernel_launch(void* const* d_in, const int* in_sizes, int n_in,
                              void* d_out, int out_size, void* d_ws, size_t ws_size,
                              hipStream_t stream) {
    const float* x      = (const float*)d_in[0];
    const float* y      = (const float*)d_in[1];
    const int*   labels = (const int*)d_in[2];
    // d_in[3] is k == 10, baked in at compile time.

    char* ws = (char*)d_ws;
    float* y2     = (float*)ws;                                   // 200 KB (pad 256 KB)
    float* pscore = (float*)(ws + 262144);                        // 8192*16*10*4 = 5.24 MB
    int*   plabel = (int*)(ws + 262144 + (size_t)N_Q * SPLITS * KNN * 4);
    int*   out    = (int*)d_out;

    y2_kernel<<<(M_PTS * 32) / 256, 256, 0, stream>>>((const float4*)y, y2);
    knn_partial<<<dim3(N_Q / Q_PER_BLOCK, SPLITS), 256, 0, stream>>>(
        x, y, labels, y2, pscore, plabel);
    knn_final<<<N_Q / 256, 256, 0, stream>>>(pscore, plabel, out);
}

// Round 3
// 855.255 us; speedup vs baseline: 6.8001x; 6.8001x over previous
//
#include <hip/hip_runtime.h>
#include <float.h>
#include <limits.h>

#define N_Q 8192
#define M_PTS 50000
#define DIM 128
#define KNN 10
#define NCLS 10
#define NCHUNK 10          // m split into 10 ragged chunks of 313/312 16-pt tiles
#define CPC 8              // candidates kept per (query, chunk)
#define NCAND (NCHUNK*CPC) // 80 candidates per query
#define NSEL 16            // exact-rescored candidates per query
#define TPL 5              // per-lane top depth (safety: C(10,6)/160^5 ~ 1e-8/query)

typedef __attribute__((ext_vector_type(8))) short bf16x8;
typedef __attribute__((ext_vector_type(4))) float f32x4;
typedef unsigned int u32;
typedef unsigned short u16;

// ---------------------------------------------------------------------------
// fp32 -> bf16 RNE conversion, 4 elems/thread, exact grids (no bounds check).
// ---------------------------------------------------------------------------
__device__ __forceinline__ u16 rne_bf16(float f) {
    u32 u = __float_as_uint(f);
    u32 r = u + 0x7FFFu + ((u >> 16) & 1u);
    return (u16)(r >> 16);
}

__global__ __launch_bounds__(256) void cvt_bf16(const float4* __restrict__ in,
                                                ushort4* __restrict__ out) {
    int t = blockIdx.x * 256 + threadIdx.x;
    float4 v = in[t];
    ushort4 o;
    o.x = rne_bf16(v.x); o.y = rne_bf16(v.y);
    o.z = rne_bf16(v.z); o.w = rne_bf16(v.w);
    out[t] = o;
}

// ---------------------------------------------------------------------------
// y2[j] = ||train_pts[j]||^2 (fp32, used by the approx filter only).
// ---------------------------------------------------------------------------
__global__ __launch_bounds__(256) void y2_kernel(const float4* __restrict__ y,
                                                 float* __restrict__ y2) {
    int t = blockIdx.x * 256 + threadIdx.x;
    int row = t >> 5;
    int lane32 = t & 31;
    float4 v = y[t];
    float p = v.x * v.x + v.y * v.y + v.z * v.z + v.w * v.w;
    #pragma unroll
    for (int off = 16; off > 0; off >>= 1) p += __shfl_xor(p, off, 64);
    if (lane32 == 0) y2[row] = p;
}

__device__ __forceinline__ int chunk_t0(int c) { return c * 312 + (c < 5 ? c : 5); }

// ---------------------------------------------------------------------------
// Filter: bf16 16x16x32 MFMA scores s = y2[j] - 2*dot (x^2 + sqrt dropped:
// order-preserving per query). Each lane holds 4 queries x 1 point per tile
// (C layout: col=lane&15 -> point, row=(lane>>4)*4+reg -> query). Score's low
// 13 mantissa bits are replaced by the chunk-relative point index, giving a
// 32-bit key whose float ordering == (quantized score, idx). Top-5 per lane
// kept with a branchless fminf/fmaxf bubble. Epilogue: LDS merge of the 16
// lane-classes -> per-(query,chunk) top-8 keys -> workspace.
// ---------------------------------------------------------------------------
__global__ __launch_bounds__(256, 4) void knn_filter(
    const u16* __restrict__ xb, const u16* __restrict__ yb,
    const float* __restrict__ y2, u32* __restrict__ ckey) {
    const int lane = threadIdx.x & 63;
    const int wid  = threadIdx.x >> 6;      // wave 0..3
    const int g    = lane >> 4;             // k-group 0..3
    const int nrow = lane & 15;             // A-row m / B-col n
    const int qw   = blockIdx.x * 64 + wid * 16;
    const int chunk = blockIdx.y;
    const int t0 = chunk_t0(chunk);
    const int tn = 312 + (chunk < 5 ? 1 : 0);
    const int p0 = t0 * 16;

    // A fragments: 16 queries x K=128, resident (16 VGPRs)
    const u16* xr = xb + (size_t)(qw + nrow) * DIM + g * 8;
    bf16x8 a0 = *(const bf16x8*)(xr);
    bf16x8 a1 = *(const bf16x8*)(xr + 32);
    bf16x8 a2 = *(const bf16x8*)(xr + 64);
    bf16x8 a3 = *(const bf16x8*)(xr + 96);

    float ts[4][TPL];
    #pragma unroll
    for (int r = 0; r < 4; ++r)
        #pragma unroll
        for (int l = 0; l < TPL; ++l) ts[r][l] = FLT_MAX;

    const u16* yr = yb + (size_t)(p0 + nrow) * DIM + g * 8;
    const float* y2p = y2 + p0 + nrow;

    for (int t = 0; t < tn; ++t) {
        bf16x8 b0 = *(const bf16x8*)(yr);
        bf16x8 b1 = *(const bf16x8*)(yr + 32);
        bf16x8 b2 = *(const bf16x8*)(yr + 64);
        bf16x8 b3 = *(const bf16x8*)(yr + 96);
        yr += 16 * DIM;
        f32x4 acc = {0.f, 0.f, 0.f, 0.f};
        acc = __builtin_amdgcn_mfma_f32_16x16x32_bf16(a0, b0, acc, 0, 0, 0);
        acc = __builtin_amdgcn_mfma_f32_16x16x32_bf16(a1, b1, acc, 0, 0, 0);
        acc = __builtin_amdgcn_mfma_f32_16x16x32_bf16(a2, b2, acc, 0, 0, 0);
        acc = __builtin_amdgcn_mfma_f32_16x16x32_bf16(a3, b3, acc, 0, 0, 0);
        float y2n = *y2p; y2p += 16;
        u32 rel = (u32)(t * 16 + nrow);     // < 5008, fits 13 bits
        #pragma unroll
        for (int r = 0; r < 4; ++r) {
            float s = fmaf(-2.0f, acc[r], y2n);
            float key = __uint_as_float((__float_as_uint(s) & 0xFFFFE000u) | rel);
            #pragma unroll
            for (int l = 0; l < TPL; ++l) {     // branchless sorted insert
                float mn = fminf(ts[r][l], key);
                key = fmaxf(ts[r][l], key);
                ts[r][l] = mn;
            }
        }
    }

    // merge 16 lane-classes -> per-query top-8
    __shared__ u32 lds[64][16 * TPL];           // 20 KB
    #pragma unroll
    for (int r = 0; r < 4; ++r) {
        int ql = wid * 16 + g * 4 + r;          // query row of this reg
        #pragma unroll
        for (int l = 0; l < TPL; ++l)
            lds[ql][nrow * TPL + l] = __float_as_uint(ts[r][l]);
    }
    __syncthreads();
    if (threadIdx.x < 64) {
        int ql = threadIdx.x;
        float bs[CPC];
        #pragma unroll
        for (int i = 0; i < CPC; ++i) bs[i] = FLT_MAX;
        for (int e = 0; e < 16 * TPL; ++e) {
            float f = __uint_as_float(lds[ql][e]);
            #pragma unroll
            for (int p = 0; p < CPC; ++p) {     // branchless bubble
                float mn = fminf(bs[p], f);
                f = fmaxf(bs[p], f);
                bs[p] = mn;
            }
        }
        u32* dst = ckey + ((size_t)(blockIdx.x * 64 + ql) * NCHUNK + chunk) * CPC;
        #pragma unroll
        for (int i = 0; i < CPC; ++i) dst[i] = __float_as_uint(bs[i]);
    }
}

// ---------------------------------------------------------------------------
// Select: per query, approx-top-16 of the 80 candidate keys; decode absolute
// point index from (chunk, 13 low bits).
// ---------------------------------------------------------------------------
__global__ __launch_bounds__(256) void knn_select(const u32* __restrict__ ckey,
                                                  int* __restrict__ sel) {
    int q = blockIdx.x * 256 + threadIdx.x;
    float bs[NSEL]; int bi[NSEL];
    #pragma unroll
    for (int i = 0; i < NSEL; ++i) { bs[i] = FLT_MAX; bi[i] = 0; }
    const u32* ck = ckey + (size_t)q * NCAND;
    for (int e = 0; e < NCAND; ++e) {
        u32 u = ck[e];
        float f = __uint_as_float(u);
        if (f < bs[NSEL - 1]) {
            int c = e >> 3;
            int id = chunk_t0(c) * 16 + (int)(u & 0x1FFFu);
            #pragma unroll
            for (int p = 0; p < NSEL; ++p) {    // swap-bubble with payload
                bool lt = f < bs[p];
                float nf = lt ? bs[p] : f;  int nid = lt ? bi[p] : id;
                bs[p] = lt ? f : bs[p];     bi[p] = lt ? id : bi[p];
                f = nf; id = nid;
            }
        }
    }
    #pragma unroll
    for (int i = 0; i < NSEL; ++i) sel[(size_t)q * NSEL + i] = bi[i];
}

// ---------------------------------------------------------------------------
// Exact rescore (fp64): one thread per (query, candidate).
// score = ||y||^2 - 2 x.y  (x^2 dropped: per-query constant).
// ---------------------------------------------------------------------------
__global__ __launch_bounds__(256) void knn_exact(const float* __restrict__ x,
                                                 const float* __restrict__ y,
                                                 const int* __restrict__ sel,
                                                 double* __restrict__ ex) {
    int t = blockIdx.x * 256 + threadIdx.x;
    int q = t >> 4;
    int idx = sel[t];
    const float* xr = x + (size_t)q * DIM;
    const float* yr = y + (size_t)idx * DIM;
    double dy2 = 0.0, dxy = 0.0;
    #pragma unroll 8
    for (int i = 0; i < DIM; ++i) {
        double yy = (double)yr[i];
        dy2 = fma(yy, yy, dy2);
        dxy = fma((double)xr[i], yy, dxy);
    }
    ex[t] = dy2 - 2.0 * dxy;
}

// ---------------------------------------------------------------------------
// Vote: exact top-10 of the 16 (ties -> lower point index, matching jax
// top_k stability), then majority vote with ties -> LARGEST class.
// ---------------------------------------------------------------------------
__global__ __launch_bounds__(256) void knn_vote(const double* __restrict__ ex,
                                                const int* __restrict__ sel,
                                                const int* __restrict__ labels,
                                                int* __restrict__ out) {
    int q = blockIdx.x * 256 + threadIdx.x;
    double ts[KNN]; int ti[KNN];
    #pragma unroll
    for (int i = 0; i < KNN; ++i) { ts[i] = 1e300; ti[i] = INT_MAX; }
    #pragma unroll
    for (int c = 0; c < NSEL; ++c) {
        double s = ex[(size_t)q * NSEL + c];
        int id = sel[(size_t)q * NSEL + c];
        #pragma unroll
        for (int p = 0; p < KNN; ++p) {         // swap-bubble, (score, idx) order
            bool lt = (s < ts[p]) || (s == ts[p] && id < ti[p]);
            double ns = lt ? ts[p] : s;  int nid = lt ? ti[p] : id;
            ts[p] = lt ? s : ts[p];      ti[p] = lt ? id : ti[p];
            s = ns; id = nid;
        }
    }
    int lab[KNN];
    #pragma unroll
    for (int i = 0; i < KNN; ++i) lab[i] = labels[ti[i]];
    int bestc = 0, bestn = -1;
    #pragma unroll
    for (int c = 0; c < NCLS; ++c) {
        int n = 0;
        #pragma unroll
        for (int i = 0; i < KNN; ++i) n += (lab[i] == c) ? 1 : 0;
        if (n >= bestn) { bestn = n; bestc = c; }   // >= : ties -> larger label
    }
    out[q] = bestc;
}

// ---------------------------------------------------------------------------
extern "C" void kernel_launch(void* const* d_in, const int* in_sizes, int n_in,
                              void* d_out, int out_size, void* d_ws, size_t ws_size,
                              hipStream_t stream) {
    const float* x      = (const float*)d_in[0];
    const float* y      = (const float*)d_in[1];
    const int*   labels = (const int*)d_in[2];
    // d_in[3] is k == 10, baked in.

    char* ws = (char*)d_ws;
    size_t off = 0;
    u16* xb = (u16*)(ws + off);     off += (size_t)N_Q * DIM * 2;      //  2.10 MB
    u16* yb = (u16*)(ws + off);     off += (size_t)M_PTS * DIM * 2;    // 12.80 MB
    float* y2 = (float*)(ws + off); off += (size_t)M_PTS * 4;          //  0.20 MB
    u32* ckey = (u32*)(ws + off);   off += (size_t)N_Q * NCAND * 4;    //  2.62 MB
    int* sel = (int*)(ws + off);    off += (size_t)N_Q * NSEL * 4;     //  0.52 MB
    double* ex = (double*)(ws + off);                                   //  1.05 MB
    int* out = (int*)d_out;

    cvt_bf16<<<N_Q * DIM / 4 / 256, 256, 0, stream>>>((const float4*)x, (ushort4*)xb);
    cvt_bf16<<<M_PTS * DIM / 4 / 256, 256, 0, stream>>>((const float4*)y, (ushort4*)yb);
    y2_kernel<<<M_PTS * 32 / 256, 256, 0, stream>>>((const float4*)y, y2);
    knn_filter<<<dim3(N_Q / 64, NCHUNK), 256, 0, stream>>>(xb, yb, y2, ckey);
    knn_select<<<N_Q / 256, 256, 0, stream>>>(ckey, sel);
    knn_exact<<<N_Q * NSEL / 256, 256, 0, stream>>>(x, y, sel, ex);
    knn_vote<<<N_Q / 256, 256, 0, stream>>>(ex, sel, labels, out);
}

// Round 4
// 392.757 us; speedup vs baseline: 14.8076x; 2.1776x over previous
//
#include <hip/hip_runtime.h>
#include <float.h>
#include <limits.h>

#define N_Q 8192
#define M_PTS 50000
#define DIM 128
#define KNN 10
#define NCLS 10
#define NCHUNK 16          // m split into 16 chunks; chunk c has 196 (c<5) or 195 tiles
#define CPC 8              // candidates kept per (query, chunk)
#define NCAND (NCHUNK*CPC) // 128 candidates per query
#define NSEL 16            // exact-rescored candidates per query
#define TPL 4              // per-lane-class top depth (fail prob ~5e-4 total)
#define QPB 128            // queries per block (4 waves x 32)

typedef __attribute__((ext_vector_type(8))) short bf16x8;
typedef __attribute__((ext_vector_type(4))) float f32x4;
typedef unsigned int u32;
typedef unsigned short u16;

__device__ __forceinline__ int chunk_t0(int c) { return c * 195 + (c < 5 ? c : 5); }

// ---------------------------------------------------------------------------
// fp32 -> bf16 RNE conversion, 4 elems/thread.
// ---------------------------------------------------------------------------
__device__ __forceinline__ u16 rne_bf16(float f) {
    u32 u = __float_as_uint(f);
    u32 r = u + 0x7FFFu + ((u >> 16) & 1u);
    return (u16)(r >> 16);
}

__global__ __launch_bounds__(256) void cvt_bf16(const float4* __restrict__ in,
                                                ushort4* __restrict__ out) {
    int t = blockIdx.x * 256 + threadIdx.x;
    float4 v = in[t];
    ushort4 o;
    o.x = rne_bf16(v.x); o.y = rne_bf16(v.y);
    o.z = rne_bf16(v.z); o.w = rne_bf16(v.w);
    out[t] = o;
}

// ---------------------------------------------------------------------------
// y2[j] = ||train_pts[j]||^2 (fp32, filter only).
// ---------------------------------------------------------------------------
__global__ __launch_bounds__(256) void y2_kernel(const float4* __restrict__ y,
                                                 float* __restrict__ y2) {
    int t = blockIdx.x * 256 + threadIdx.x;
    int row = t >> 5;
    int lane32 = t & 31;
    float4 v = y[t];
    float p = v.x * v.x + v.y * v.y + v.z * v.z + v.w * v.w;
    #pragma unroll
    for (int off = 16; off > 0; off >>= 1) p += __shfl_xor(p, off, 64);
    if (lane32 == 0) y2[row] = p;
}

// ---------------------------------------------------------------------------
// Filter: bf16 MFMA scores with LDS-staged B tiles (double-buffered
// global_load_lds, m97 pattern). Each block: 128 queries x one m-chunk.
// Wave = 32 queries (two A-sets sharing each B fragment). B tile (16 pts x
// 256 B) staged once per block per tile; XOR chunk swizzle (slot c^row)
// makes the ds_read_b128 fragment reads 2-way-conflict (free). Scores keyed
// with 12-bit chunk-relative index stuffed in the mantissa; per-lane-class
// top-4 kept branchless; epilogue merges 16 lane-classes -> per-(q,chunk)
// top-8 via padded-LDS (stride 65: conflict-free).
// ---------------------------------------------------------------------------
__global__ __launch_bounds__(256, 4) void knn_filter(
    const u16* __restrict__ xb, const u16* __restrict__ yb,
    const float* __restrict__ y2, u32* __restrict__ ckey) {
    const int lane = threadIdx.x & 63;
    const int wid  = threadIdx.x >> 6;      // wave 0..3
    const int g    = lane >> 4;             // k-group 0..3
    const int nrow = lane & 15;             // point-in-tile (B col / C col)
    const int chunk = blockIdx.x;           // grid.x=16 -> block_id%8 pins XCD
    const int qb    = blockIdx.y;
    const int t0 = chunk_t0(chunk);
    const int tn = (chunk < 5) ? 196 : 195;
    const int p0 = t0 * 16;
    const int qw = qb * QPB + wid * 32;

    // A fragments: 2 sets x 4 frags (k = 32*b + 8*g + e), 32 VGPRs total
    bf16x8 a[2][4];
    #pragma unroll
    for (int s = 0; s < 2; ++s) {
        const u16* xr = xb + (size_t)(qw + s * 16 + nrow) * DIM + g * 8;
        #pragma unroll
        for (int b = 0; b < 4; ++b) a[s][b] = *(const bf16x8*)(xr + b * 32);
    }

    float ts[8][TPL];
    #pragma unroll
    for (int r = 0; r < 8; ++r)
        #pragma unroll
        for (int l = 0; l < TPL; ++l) ts[r][l] = FLT_MAX;

    // LDS: stage double-buffer (2 x 1024 u32 = 8 KB) overlaid at the front of
    // the 33 KB merge region (merge used only after the loop).
    __shared__ u32 smem[QPB * 65];          // 33280 B

    // Staging source: wave w fetches rows [4w,4w+4) of each tile; lane l ->
    // row r = 4w + (l>>4), chunk-slot s = l&15 holds global chunk s^r.
    const int srow = wid * 4 + (lane >> 4);
    const int schunk = (lane & 15) ^ (srow & 15);
    const u16* ysrc = yb + (size_t)(p0 + srow) * DIM + schunk * 8;

    typedef const __attribute__((address_space(1))) void* gp1;
    typedef __attribute__((address_space(3))) void* lp3;

    // prologue: stage tile 0 into buf 0
    __builtin_amdgcn_global_load_lds((gp1)ysrc, (lp3)(smem + wid * 256), 16, 0, 0);
    ysrc += 16 * DIM;
    __syncthreads();

    const float* y2p = y2 + p0 + nrow;
    u32 rel = (u32)nrow;

    for (int t = 0; t < tn; ++t) {
        u32* buf = smem + (t & 1) * 1024;
        // stage next tile into the other buffer (completed by next barrier)
        if (t + 1 < tn) {
            __builtin_amdgcn_global_load_lds(
                (gp1)ysrc, (lp3)(smem + ((t + 1) & 1) * 1024 + wid * 256), 16, 0, 0);
            ysrc += 16 * DIM;
        }
        // B fragments from LDS (swizzled slot (g+4b)^nrow -> global chunk g+4b)
        bf16x8 b0 = *(const bf16x8*)(buf + nrow * 64 + (((g + 0) ^ nrow) & 15) * 4);
        bf16x8 b1 = *(const bf16x8*)(buf + nrow * 64 + (((g + 4) ^ nrow) & 15) * 4);
        bf16x8 b2 = *(const bf16x8*)(buf + nrow * 64 + (((g + 8) ^ nrow) & 15) * 4);
        bf16x8 b3 = *(const bf16x8*)(buf + nrow * 64 + (((g + 12) ^ nrow) & 15) * 4);

        f32x4 acc0 = {0.f, 0.f, 0.f, 0.f};
        f32x4 acc1 = {0.f, 0.f, 0.f, 0.f};
        acc0 = __builtin_amdgcn_mfma_f32_16x16x32_bf16(a[0][0], b0, acc0, 0, 0, 0);
        acc0 = __builtin_amdgcn_mfma_f32_16x16x32_bf16(a[0][1], b1, acc0, 0, 0, 0);
        acc0 = __builtin_amdgcn_mfma_f32_16x16x32_bf16(a[0][2], b2, acc0, 0, 0, 0);
        acc0 = __builtin_amdgcn_mfma_f32_16x16x32_bf16(a[0][3], b3, acc0, 0, 0, 0);
        acc1 = __builtin_amdgcn_mfma_f32_16x16x32_bf16(a[1][0], b0, acc1, 0, 0, 0);
        acc1 = __builtin_amdgcn_mfma_f32_16x16x32_bf16(a[1][1], b1, acc1, 0, 0, 0);
        acc1 = __builtin_amdgcn_mfma_f32_16x16x32_bf16(a[1][2], b2, acc1, 0, 0, 0);
        acc1 = __builtin_amdgcn_mfma_f32_16x16x32_bf16(a[1][3], b3, acc1, 0, 0, 0);

        float y2n = *y2p; y2p += 16;
        #pragma unroll
        for (int s = 0; s < 2; ++s) {
            #pragma unroll
            for (int r = 0; r < 4; ++r) {
                float sc = fmaf(-2.0f, (s == 0) ? acc0[r] : acc1[r], y2n);
                float key = __uint_as_float((__float_as_uint(sc) & 0xFFFFF000u) | rel);
                #pragma unroll
                for (int l = 0; l < TPL; ++l) {   // branchless sorted insert
                    float mn = fminf(ts[s * 4 + r][l], key);
                    key = fmaxf(ts[s * 4 + r][l], key);
                    ts[s * 4 + r][l] = mn;
                }
            }
        }
        rel += 16;
        __syncthreads();   // drains stage vmcnt (compiler) + protects buf reuse
    }

    // ---- merge 16 lane-classes -> per-query top-8 ----
    #pragma unroll
    for (int s = 0; s < 2; ++s)
        #pragma unroll
        for (int r = 0; r < 4; ++r) {
            int ql = wid * 32 + s * 16 + g * 4 + r;
            #pragma unroll
            for (int l = 0; l < TPL; ++l)
                smem[ql * 65 + nrow * TPL + l] = __float_as_uint(ts[s * 4 + r][l]);
        }
    __syncthreads();
    if (threadIdx.x < QPB) {
        int ql = threadIdx.x;
        float bs[CPC];
        #pragma unroll
        for (int i = 0; i < CPC; ++i) bs[i] = FLT_MAX;
        for (int e = 0; e < 16 * TPL; ++e) {      // stride-65 reads: conflict-free
            float f = __uint_as_float(smem[ql * 65 + e]);
            #pragma unroll
            for (int p = 0; p < CPC; ++p) {
                float mn = fminf(bs[p], f);
                f = fmaxf(bs[p], f);
                bs[p] = mn;
            }
        }
        u32* dst = ckey + ((size_t)(qb * QPB + ql) * NCHUNK + chunk) * CPC;
        #pragma unroll
        for (int i = 0; i < CPC; ++i) dst[i] = __float_as_uint(bs[i]);
    }
}

// ---------------------------------------------------------------------------
// Select: per query, approx-top-16 of the 128 candidate keys; decode absolute
// point index from (chunk, 12 low bits).
// ---------------------------------------------------------------------------
__global__ __launch_bounds__(256) void knn_select(const u32* __restrict__ ckey,
                                                  int* __restrict__ sel) {
    int q = blockIdx.x * 256 + threadIdx.x;
    float bs[NSEL]; int bi[NSEL];
    #pragma unroll
    for (int i = 0; i < NSEL; ++i) { bs[i] = FLT_MAX; bi[i] = 0; }
    const u32* ck = ckey + (size_t)q * NCAND;
    for (int e = 0; e < NCAND; ++e) {
        u32 u = ck[e];
        float f = __uint_as_float(u);
        if (f < bs[NSEL - 1]) {
            int c = e >> 3;
            int id = chunk_t0(c) * 16 + (int)(u & 0xFFFu);
            #pragma unroll
            for (int p = 0; p < NSEL; ++p) {
                bool lt = f < bs[p];
                float nf = lt ? bs[p] : f;  int nid = lt ? bi[p] : id;
                bs[p] = lt ? f : bs[p];     bi[p] = lt ? id : bi[p];
                f = nf; id = nid;
            }
        }
    }
    #pragma unroll
    for (int i = 0; i < NSEL; ++i) sel[(size_t)q * NSEL + i] = bi[i];
}

// ---------------------------------------------------------------------------
// Exact rescore (fp64): one thread per (query, candidate).
// ---------------------------------------------------------------------------
__global__ __launch_bounds__(256) void knn_exact(const float* __restrict__ x,
                                                 const float* __restrict__ y,
                                                 const int* __restrict__ sel,
                                                 double* __restrict__ ex) {
    int t = blockIdx.x * 256 + threadIdx.x;
    int q = t >> 4;
    int idx = sel[t];
    const float* xr = x + (size_t)q * DIM;
    const float* yr = y + (size_t)idx * DIM;
    double dy2 = 0.0, dxy = 0.0;
    #pragma unroll 8
    for (int i = 0; i < DIM; ++i) {
        double yy = (double)yr[i];
        dy2 = fma(yy, yy, dy2);
        dxy = fma((double)xr[i], yy, dxy);
    }
    ex[t] = dy2 - 2.0 * dxy;
}

// ---------------------------------------------------------------------------
// Vote: exact top-10 of the 16 (ties -> lower point index = jax top_k
// stability), then majority vote, ties -> LARGEST class.
// ---------------------------------------------------------------------------
__global__ __launch_bounds__(256) void knn_vote(const double* __restrict__ ex,
                                                const int* __restrict__ sel,
                                                const int* __restrict__ labels,
                                                int* __restrict__ out) {
    int q = blockIdx.x * 256 + threadIdx.x;
    double ts[KNN]; int ti[KNN];
    #pragma unroll
    for (int i = 0; i < KNN; ++i) { ts[i] = 1e300; ti[i] = INT_MAX; }
    #pragma unroll
    for (int c = 0; c < NSEL; ++c) {
        double s = ex[(size_t)q * NSEL + c];
        int id = sel[(size_t)q * NSEL + c];
        #pragma unroll
        for (int p = 0; p < KNN; ++p) {
            bool lt = (s < ts[p]) || (s == ts[p] && id < ti[p]);
            double ns = lt ? ts[p] : s;  int nid = lt ? ti[p] : id;
            ts[p] = lt ? s : ts[p];      ti[p] = lt ? id : ti[p];
            s = ns; id = nid;
        }
    }
    int lab[KNN];
    #pragma unroll
    for (int i = 0; i < KNN; ++i) lab[i] = labels[ti[i]];
    int bestc = 0, bestn = -1;
    #pragma unroll
    for (int c = 0; c < NCLS; ++c) {
        int n = 0;
        #pragma unroll
        for (int i = 0; i < KNN; ++i) n += (lab[i] == c) ? 1 : 0;
        if (n >= bestn) { bestn = n; bestc = c; }
    }
    out[q] = bestc;
}

// ---------------------------------------------------------------------------
extern "C" void kernel_launch(void* const* d_in, const int* in_sizes, int n_in,
                              void* d_out, int out_size, void* d_ws, size_t ws_size,
                              hipStream_t stream) {
    const float* x      = (const float*)d_in[0];
    const float* y      = (const float*)d_in[1];
    const int*   labels = (const int*)d_in[2];
    // d_in[3] is k == 10, baked in.

    char* ws = (char*)d_ws;
    size_t off = 0;
    u16* xb = (u16*)(ws + off);     off += (size_t)N_Q * DIM * 2;      //  2.10 MB
    u16* yb = (u16*)(ws + off);     off += (size_t)M_PTS * DIM * 2;    // 12.80 MB
    float* y2 = (float*)(ws + off); off += (size_t)M_PTS * 4;          //  0.20 MB
    u32* ckey = (u32*)(ws + off);   off += (size_t)N_Q * NCAND * 4;    //  4.19 MB
    int* sel = (int*)(ws + off);    off += (size_t)N_Q * NSEL * 4;     //  0.52 MB
    double* ex = (double*)(ws + off);                                   //  1.05 MB
    int* out = (int*)d_out;

    cvt_bf16<<<N_Q * DIM / 4 / 256, 256, 0, stream>>>((const float4*)x, (ushort4*)xb);
    cvt_bf16<<<M_PTS * DIM / 4 / 256, 256, 0, stream>>>((const float4*)y, (ushort4*)yb);
    y2_kernel<<<M_PTS * 32 / 256, 256, 0, stream>>>((const float4*)y, y2);
    knn_filter<<<dim3(NCHUNK, N_Q / QPB), 256, 0, stream>>>(xb, yb, y2, ckey);
    knn_select<<<N_Q / 256, 256, 0, stream>>>(ckey, sel);
    knn_exact<<<N_Q * NSEL / 256, 256, 0, stream>>>(x, y, sel, ex);
    knn_vote<<<N_Q / 256, 256, 0, stream>>>(ex, sel, labels, out);
}

// Round 5
// 306.122 us; speedup vs baseline: 18.9982x; 1.2830x over previous
//
#include <hip/hip_runtime.h>
#include <float.h>
#include <limits.h>

#define N_Q 8192
#define M_PTS 50000
#define DIM 128
#define KNN 10
#define NCLS 10
#define NCHUNK 12          // 12 chunks: c<5 -> 261 tiles, else 260 (3125 total)
#define CPC 8              // candidates kept per (query, chunk)
#define NCAND (NCHUNK*CPC) // 96 candidates per query
#define NSEL 16            // exact-rescored candidates per query
#define TPL 4              // per-lane-class top depth
#define QPB 128            // queries per block (4 waves x 32)
#define XN4 (N_Q*DIM/4)    // 262144 float4 in x
#define YN4 (M_PTS*DIM/4)  // 1600000 float4 in y

typedef __attribute__((ext_vector_type(8))) short bf16x8;
typedef __attribute__((ext_vector_type(4))) float f32x4;
typedef unsigned int u32;
typedef unsigned short u16;

__device__ __forceinline__ int chunk_t0(int c) { return c * 260 + (c < 5 ? c : 5); }

__device__ __forceinline__ u16 rne_bf16(float f) {
    u32 u = __float_as_uint(f);
    u32 r = u + 0x7FFFu + ((u >> 16) & 1u);
    return (u16)(r >> 16);
}

// ---------------------------------------------------------------------------
// Prep: bf16-convert x and y, and fold y2 = ||y_j||^2 out of the same y load.
// Grid is exact: (XN4+YN4)/256 = 7274 blocks, wave-aligned split.
// ---------------------------------------------------------------------------
__global__ __launch_bounds__(256) void prep_kernel(
    const float4* __restrict__ x4, const float4* __restrict__ y4,
    ushort4* __restrict__ xb4, ushort4* __restrict__ yb4,
    float* __restrict__ y2) {
    int t = blockIdx.x * 256 + threadIdx.x;
    if (t < XN4) {
        float4 v = x4[t];
        ushort4 o;
        o.x = rne_bf16(v.x); o.y = rne_bf16(v.y);
        o.z = rne_bf16(v.z); o.w = rne_bf16(v.w);
        xb4[t] = o;
    } else {
        int j = t - XN4;
        float4 v = y4[j];
        ushort4 o;
        o.x = rne_bf16(v.x); o.y = rne_bf16(v.y);
        o.z = rne_bf16(v.z); o.w = rne_bf16(v.w);
        yb4[j] = o;
        float p = v.x * v.x + v.y * v.y + v.z * v.z + v.w * v.w;
        #pragma unroll
        for (int off = 16; off > 0; off >>= 1) p += __shfl_xor(p, off, 64);
        if ((j & 31) == 0) y2[j >> 5] = p;
    }
}

// ---------------------------------------------------------------------------
// Filter: bf16 MFMA scores, LDS-staged B tiles (double-buffered
// global_load_lds), 128 queries x one m-chunk per block, wave = 32 queries
// (two A-sets share each B fragment). Per-lane-class top-4 kept with a
// min+med3 sorted-insert (4 VALU/score). 13-bit chunk-relative index stuffed
// in the key mantissa. launch_bounds(256,3): 170-reg budget so ts/a stay in
// arch VGPRs (at (256,4) the allocator spilled ts to AGPRs -> ~128
// v_accvgpr_read/write per iter, the round-4 VALU blowup).
// ---------------------------------------------------------------------------
__global__ __launch_bounds__(256, 3) void knn_filter(
    const u16* __restrict__ xb, const u16* __restrict__ yb,
    const float* __restrict__ y2, u32* __restrict__ ckey) {
    const int lane = threadIdx.x & 63;
    const int wid  = threadIdx.x >> 6;      // wave 0..3
    const int g    = lane >> 4;             // k-group 0..3
    const int nrow = lane & 15;             // point-in-tile (B col / C col)
    const int chunk = blockIdx.x;           // grid 12x64 = 768 = 3 blocks/CU
    const int qb    = blockIdx.y;
    const int t0 = chunk_t0(chunk);
    const int tn = (chunk < 5) ? 261 : 260;
    const int p0 = t0 * 16;
    const int qw = qb * QPB + wid * 32;

    // A fragments: 2 sets x 4 frags (k = 32*b + 8*g + e), 32 VGPRs
    bf16x8 a[2][4];
    #pragma unroll
    for (int s = 0; s < 2; ++s) {
        const u16* xr = xb + (size_t)(qw + s * 16 + nrow) * DIM + g * 8;
        #pragma unroll
        for (int b = 0; b < 4; ++b) a[s][b] = *(const bf16x8*)(xr + b * 32);
    }

    float ts[8][TPL];
    #pragma unroll
    for (int r = 0; r < 8; ++r)
        #pragma unroll
        for (int l = 0; l < TPL; ++l) ts[r][l] = FLT_MAX;

    // LDS: staging double-buffer (2 x 1024 u32 = 8 KB) overlaid on the front
    // of the 33 KB merge region (merge only runs after the loop).
    __shared__ u32 smem[QPB * 65];          // 33280 B
    u32* buf0 = smem;
    u32* buf1 = smem + 1024;

    // Stage mapping: wave w fetches rows [4w,4w+4); lane l -> row 4w+(l>>4),
    // chunk-slot l&15 holds global chunk (l&15)^row (XOR swizzle -> the
    // ds_read_b128 fragment reads are 2-way = free).
    const int srow = wid * 4 + (lane >> 4);
    const int schunk = (lane & 15) ^ srow;
    const u16* ysrc = yb + (size_t)(p0 + srow) * DIM + schunk * 8;

    typedef const __attribute__((address_space(1))) void* gp1;
    typedef __attribute__((address_space(3))) void* lp3;

    __builtin_amdgcn_global_load_lds((gp1)ysrc, (lp3)(buf0 + wid * 256), 16, 0, 0);
    ysrc += 16 * DIM;
    __syncthreads();

    const float* y2c = y2 + p0;             // y2c[rel] = y2 of (tile,nrow)

    auto compute = [&](const u32* buf, u32 rel) {
        bf16x8 b0 = *(const bf16x8*)(buf + nrow * 64 + (((g + 0) ^ nrow) & 15) * 4);
        bf16x8 b1 = *(const bf16x8*)(buf + nrow * 64 + (((g + 4) ^ nrow) & 15) * 4);
        bf16x8 b2 = *(const bf16x8*)(buf + nrow * 64 + (((g + 8) ^ nrow) & 15) * 4);
        bf16x8 b3 = *(const bf16x8*)(buf + nrow * 64 + (((g + 12) ^ nrow) & 15) * 4);
        f32x4 acc0 = {0.f, 0.f, 0.f, 0.f};
        f32x4 acc1 = {0.f, 0.f, 0.f, 0.f};
        acc0 = __builtin_amdgcn_mfma_f32_16x16x32_bf16(a[0][0], b0, acc0, 0, 0, 0);
        acc0 = __builtin_amdgcn_mfma_f32_16x16x32_bf16(a[0][1], b1, acc0, 0, 0, 0);
        acc0 = __builtin_amdgcn_mfma_f32_16x16x32_bf16(a[0][2], b2, acc0, 0, 0, 0);
        acc0 = __builtin_amdgcn_mfma_f32_16x16x32_bf16(a[0][3], b3, acc0, 0, 0, 0);
        acc1 = __builtin_amdgcn_mfma_f32_16x16x32_bf16(a[1][0], b0, acc1, 0, 0, 0);
        acc1 = __builtin_amdgcn_mfma_f32_16x16x32_bf16(a[1][1], b1, acc1, 0, 0, 0);
        acc1 = __builtin_amdgcn_mfma_f32_16x16x32_bf16(a[1][2], b2, acc1, 0, 0, 0);
        acc1 = __builtin_amdgcn_mfma_f32_16x16x32_bf16(a[1][3], b3, acc1, 0, 0, 0);
        float y2n = y2c[rel];
        #pragma unroll
        for (int s = 0; s < 2; ++s) {
            #pragma unroll
            for (int r = 0; r < 4; ++r) {
                const int i = s * 4 + r;
                float sc = fmaf(-2.0f, (s == 0) ? acc0[r] : acc1[r], y2n);
                float key = __uint_as_float((__float_as_uint(sc) & 0xFFFFE000u) | rel);
                // sorted top-4 insert: 1 min + 3 med3
                float o0 = ts[i][0], o1 = ts[i][1], o2 = ts[i][2];
                ts[i][0] = fminf(o0, key);
                ts[i][1] = __builtin_amdgcn_fmed3f(key, o0, o1);
                ts[i][2] = __builtin_amdgcn_fmed3f(key, o1, o2);
                ts[i][3] = __builtin_amdgcn_fmed3f(key, o2, ts[i][3]);
            }
        }
    };

    u32 rel = (u32)nrow;
    const int T = tn & ~1;
    for (int t = 0; t < T; t += 2) {
        if (t + 1 < tn) {
            __builtin_amdgcn_global_load_lds((gp1)ysrc, (lp3)(buf1 + wid * 256), 16, 0, 0);
            ysrc += 16 * DIM;
        }
        compute(buf0, rel);
        __syncthreads();
        if (t + 2 < tn) {
            __builtin_amdgcn_global_load_lds((gp1)ysrc, (lp3)(buf0 + wid * 256), 16, 0, 0);
            ysrc += 16 * DIM;
        }
        compute(buf1, rel + 16);
        __syncthreads();
        rel += 32;
    }
    if (tn & 1) {
        compute(buf0, rel);
        __syncthreads();
    }

    // ---- merge 16 lane-classes -> per-query top-8 ----
    #pragma unroll
    for (int s = 0; s < 2; ++s)
        #pragma unroll
        for (int r = 0; r < 4; ++r) {
            int ql = wid * 32 + s * 16 + g * 4 + r;
            #pragma unroll
            for (int l = 0; l < TPL; ++l)
                smem[ql * 65 + nrow * TPL + l] = __float_as_uint(ts[s * 4 + r][l]);
        }
    __syncthreads();
    if (threadIdx.x < QPB) {
        int ql = threadIdx.x;
        float bs[CPC];
        #pragma unroll
        for (int i = 0; i < CPC; ++i) bs[i] = FLT_MAX;
        for (int e = 0; e < 16 * TPL; ++e) {      // stride-65: conflict-free
            float f = __uint_as_float(smem[ql * 65 + e]);
            #pragma unroll
            for (int p = 0; p < CPC; ++p) {
                float mn = fminf(bs[p], f);
                f = fmaxf(bs[p], f);
                bs[p] = mn;
            }
        }
        u32* dst = ckey + ((size_t)(qb * QPB + ql) * NCHUNK + chunk) * CPC;
        #pragma unroll
        for (int i = 0; i < CPC; ++i) dst[i] = __float_as_uint(bs[i]);
    }
}

// ---------------------------------------------------------------------------
// Select: per query, approx-top-16 of the 96 candidate keys; decode absolute
// point index from (chunk, 13 low bits).
// ---------------------------------------------------------------------------
__global__ __launch_bounds__(256) void knn_select(const u32* __restrict__ ckey,
                                                  int* __restrict__ sel) {
    int q = blockIdx.x * 256 + threadIdx.x;
    float bs[NSEL]; int bi[NSEL];
    #pragma unroll
    for (int i = 0; i < NSEL; ++i) { bs[i] = FLT_MAX; bi[i] = 0; }
    const u32* ck = ckey + (size_t)q * NCAND;
    for (int e = 0; e < NCAND; ++e) {
        u32 u = ck[e];
        float f = __uint_as_float(u);
        if (f < bs[NSEL - 1]) {
            int c = e >> 3;
            int id = chunk_t0(c) * 16 + (int)(u & 0x1FFFu);
            #pragma unroll
            for (int p = 0; p < NSEL; ++p) {
                bool lt = f < bs[p];
                float nf = lt ? bs[p] : f;  int nid = lt ? bi[p] : id;
                bs[p] = lt ? f : bs[p];     bi[p] = lt ? id : bi[p];
                f = nf; id = nid;
            }
        }
    }
    #pragma unroll
    for (int i = 0; i < NSEL; ++i) sel[(size_t)q * NSEL + i] = bi[i];
}

// ---------------------------------------------------------------------------
// Exact rescore (fp64): one thread per (query, candidate).
// ---------------------------------------------------------------------------
__global__ __launch_bounds__(256) void knn_exact(const float* __restrict__ x,
                                                 const float* __restrict__ y,
                                                 const int* __restrict__ sel,
                                                 double* __restrict__ ex) {
    int t = blockIdx.x * 256 + threadIdx.x;
    int q = t >> 4;
    int idx = sel[t];
    const float* xr = x + (size_t)q * DIM;
    const float* yr = y + (size_t)idx * DIM;
    double dy2 = 0.0, dxy = 0.0;
    #pragma unroll 8
    for (int i = 0; i < DIM; ++i) {
        double yy = (double)yr[i];
        dy2 = fma(yy, yy, dy2);
        dxy = fma((double)xr[i], yy, dxy);
    }
    ex[t] = dy2 - 2.0 * dxy;
}

// ---------------------------------------------------------------------------
// Vote: exact top-10 of the 16 (ties -> lower point index = jax top_k
// stability), then majority vote, ties -> LARGEST class.
// ---------------------------------------------------------------------------
__global__ __launch_bounds__(256) void knn_vote(const double* __restrict__ ex,
                                                const int* __restrict__ sel,
                                                const int* __restrict__ labels,
                                                int* __restrict__ out) {
    int q = blockIdx.x * 256 + threadIdx.x;
    double ts[KNN]; int ti[KNN];
    #pragma unroll
    for (int i = 0; i < KNN; ++i) { ts[i] = 1e300; ti[i] = INT_MAX; }
    #pragma unroll
    for (int c = 0; c < NSEL; ++c) {
        double s = ex[(size_t)q * NSEL + c];
        int id = sel[(size_t)q * NSEL + c];
        #pragma unroll
        for (int p = 0; p < KNN; ++p) {
            bool lt = (s < ts[p]) || (s == ts[p] && id < ti[p]);
            double ns = lt ? ts[p] : s;  int nid = lt ? ti[p] : id;
            ts[p] = lt ? s : ts[p];      ti[p] = lt ? id : ti[p];
            s = ns; id = nid;
        }
    }
    int lab[KNN];
    #pragma unroll
    for (int i = 0; i < KNN; ++i) lab[i] = labels[ti[i]];
    int bestc = 0, bestn = -1;
    #pragma unroll
    for (int c = 0; c < NCLS; ++c) {
        int n = 0;
        #pragma unroll
        for (int i = 0; i < KNN; ++i) n += (lab[i] == c) ? 1 : 0;
        if (n >= bestn) { bestn = n; bestc = c; }
    }
    out[q] = bestc;
}

// ---------------------------------------------------------------------------
extern "C" void kernel_launch(void* const* d_in, const int* in_sizes, int n_in,
                              void* d_out, int out_size, void* d_ws, size_t ws_size,
                              hipStream_t stream) {
    const float* x      = (const float*)d_in[0];
    const float* y      = (const float*)d_in[1];
    const int*   labels = (const int*)d_in[2];
    // d_in[3] is k == 10, baked in.

    char* ws = (char*)d_ws;
    size_t off = 0;
    u16* xb = (u16*)(ws + off);     off += (size_t)N_Q * DIM * 2;      //  2.10 MB
    u16* yb = (u16*)(ws + off);     off += (size_t)M_PTS * DIM * 2;    // 12.80 MB
    float* y2 = (float*)(ws + off); off += (size_t)M_PTS * 4;          //  0.20 MB
    u32* ckey = (u32*)(ws + off);   off += (size_t)N_Q * NCAND * 4;    //  3.15 MB
    int* sel = (int*)(ws + off);    off += (size_t)N_Q * NSEL * 4;     //  0.52 MB
    double* ex = (double*)(ws + off);                                   //  1.05 MB
    int* out = (int*)d_out;

    prep_kernel<<<(XN4 + YN4) / 256, 256, 0, stream>>>(
        (const float4*)x, (const float4*)y, (ushort4*)xb, (ushort4*)yb, y2);
    knn_filter<<<dim3(NCHUNK, N_Q / QPB), 256, 0, stream>>>(xb, yb, y2, ckey);
    knn_select<<<N_Q / 256, 256, 0, stream>>>(ckey, sel);
    knn_exact<<<N_Q * NSEL / 256, 256, 0, stream>>>(x, y, sel, ex);
    knn_vote<<<N_Q / 256, 256, 0, stream>>>(ex, sel, labels, out);
}